// Round 9
// baseline (219.133 us; speedup 1.0000x reference)
//
#include <hip/hip_runtime.h>

typedef __bf16 bf16_t;
typedef bf16_t bf16x2 __attribute__((ext_vector_type(2)));
typedef bf16_t bf16x8 __attribute__((ext_vector_type(8)));
typedef float  floatx16 __attribute__((ext_vector_type(16)));
typedef unsigned int uintx4 __attribute__((ext_vector_type(4)));

constexpr int Sq = 2048, Dq = 64;
constexpr int QW = 32;            // q-rows per wave-task
constexpr int KVB = 32;           // kv-tile per loop step
constexpr int NT = Sq / QW;       // 64 tasks per head
constexpr float SCALE_LOG2E = 0.125f * 1.44269504088896340736f;

// R9: WAVE-INDEPENDENT streaming flash attention.
// R0-R8 evidence: no pipe ever >25%; every chain-lengthening or
// stream-reducing variant lost; LDS-BW theory refuted by R8 (conflicts/traffic
// halved, 36% slower). Surviving theory: serial dependency chain at ~2
// effective streams/SIMD, caused by barrier-coupled 4-wave blocks.
// This kernel: each WAVE is an independent task (32 q-rows, R8-verified
// 32x32 swapped-QK core). K and V feed MFMA fragments DIRECTLY from
// global->registers (D=64: K 8xfloat4/tile coalesced; V 32 scalar/tile,
// 2x128B segments per inst). NO loop LDS, NO loop barriers, NO staging.
// Split-K parity pairs (2 waves/block) double streams: 4096 waves = 16/CU
// = 4 independent streams per SIMD; one 8.3KB-LDS combine per task.
// Cost: K/V re-read ~1.06GB via L2 (XCD-local: id%8=bh%8) -> ~31us L2 floor.
// Balance: task j = (m&1) ? 63-m/2 : m/2 interleaves heavy/light along
// id-space, so any contiguous or round-robin dispatch gives each CU a mix.
struct Smem { float Op[QW][Dq]; float den[QW]; };   // 8320 B

static __device__ __forceinline__ bf16x8 cvt8(const float4& a, const float4& b) {
    bf16x8 w;
    w[0] = (bf16_t)a.x; w[1] = (bf16_t)a.y; w[2] = (bf16_t)a.z; w[3] = (bf16_t)a.w;
    w[4] = (bf16_t)b.x; w[5] = (bf16_t)b.y; w[6] = (bf16_t)b.z; w[7] = (bf16_t)b.w;
    return w;
}
static __device__ __forceinline__ bf16x8 cvt8s(const float4& a, const float4& b) {
    bf16x8 w;
    w[0] = (bf16_t)(a.x * SCALE_LOG2E); w[1] = (bf16_t)(a.y * SCALE_LOG2E);
    w[2] = (bf16_t)(a.z * SCALE_LOG2E); w[3] = (bf16_t)(a.w * SCALE_LOG2E);
    w[4] = (bf16_t)(b.x * SCALE_LOG2E); w[5] = (bf16_t)(b.y * SCALE_LOG2E);
    w[6] = (bf16_t)(b.z * SCALE_LOG2E); w[7] = (bf16_t)(b.w * SCALE_LOG2E);
    return w;
}
static __device__ __forceinline__ unsigned int pkbf(float lo, float hi) {
    bf16x2 t; t[0] = (bf16_t)lo; t[1] = (bf16_t)hi;
    return __builtin_bit_cast(unsigned int, t);
}

#define SUM16(p) (((((p)[0]+(p)[1])+((p)[2]+(p)[3]))+(((p)[4]+(p)[5])+((p)[6]+(p)[7]))) \
                + ((((p)[8]+(p)[9])+((p)[10]+(p)[11]))+(((p)[12]+(p)[13])+((p)[14]+(p)[15]))))

__global__ __launch_bounds__(128, 4) void flash_attn_kernel(
    const float* __restrict__ Q, const float* __restrict__ K,
    const float* __restrict__ V, float* __restrict__ O)
{
    __shared__ Smem sm;

    const int tid  = threadIdx.x;
    const int grp  = tid >> 6;          // wave = kv-parity
    const int lane = tid & 63;
    const int hi   = lane >> 5;
    const int l31  = lane & 31;

    const int id = blockIdx.x;
    const int g  = id >> 3;                       // 0..255
    const int bh = (id & 7) + ((g >> 6) << 3);    // id%8 = bh%8 (XCD affinity)
    const int m  = g & 63;
    const int j  = (m & 1) ? (NT - 1 - (m >> 1)) : (m >> 1);   // q-tile task
    const long base = (long)bh * Sq * Dq;
    const long qb   = base + (long)j * QW * Dq;

    // ---- Q fragments (B-operand of S^T = K*Q^T): lane l31 = q-col ----
    bf16x8 qf0, qf1, qf2, qf3;
    {
        const float* qp = &Q[qb + (long)l31 * Dq + 8 * hi];
        qf0 = cvt8s(*(const float4*)&qp[0],  *(const float4*)&qp[4]);
        qf1 = cvt8s(*(const float4*)&qp[16], *(const float4*)&qp[20]);
        qf2 = cvt8s(*(const float4*)&qp[32], *(const float4*)&qp[36]);
        qf3 = cvt8s(*(const float4*)&qp[48], *(const float4*)&qp[52]);
    }

    float l_lane = 0.f;
    floatx16 oacc0 = (floatx16)0.f, oacc1 = (floatx16)0.f;

    for (int t = grp; t <= j; t += 2) {
        const long kb = base + (long)t * KVB * Dq;

        // ---- K raw loads (A-operand rows: lane l31 = k-row) ----
        const float* kp = &K[kb + (long)l31 * Dq + 8 * hi];
        const float4 k00 = *(const float4*)&kp[0],  k01 = *(const float4*)&kp[4];
        const float4 k10 = *(const float4*)&kp[16], k11 = *(const float4*)&kp[20];
        const float4 k20 = *(const float4*)&kp[32], k21 = *(const float4*)&kp[36];
        const float4 k30 = *(const float4*)&kp[48], k31 = *(const float4*)&kp[52];

        // ---- V raw loads (B-operand cols: lane l31 = d; rows 8hi+jj, 16+8hi+jj) ----
        const float* vp = &V[kb + (long)(8 * hi) * Dq];
        float va[16], vb[16];
        #pragma unroll
        for (int jj = 0; jj < 8; ++jj) {
            va[jj]     = vp[jj * Dq + l31];
            va[8 + jj] = vp[(16 + jj) * Dq + l31];
            vb[jj]     = vp[jj * Dq + 32 + l31];
            vb[8 + jj] = vp[(16 + jj) * Dq + 32 + l31];
        }

        // ---- S^T = K * Q^T (4 d-steps) ----
        const bf16x8 kf0 = cvt8(k00, k01), kf1 = cvt8(k10, k11);
        const bf16x8 kf2 = cvt8(k20, k21), kf3 = cvt8(k30, k31);
        floatx16 s0 = (floatx16)0.f;
        __builtin_amdgcn_s_setprio(1);
        s0 = __builtin_amdgcn_mfma_f32_32x32x16_bf16(kf0, qf0, s0, 0, 0, 0);
        s0 = __builtin_amdgcn_mfma_f32_32x32x16_bf16(kf1, qf1, s0, 0, 0, 0);
        s0 = __builtin_amdgcn_mfma_f32_32x32x16_bf16(kf2, qf2, s0, 0, 0, 0);
        s0 = __builtin_amdgcn_mfma_f32_32x32x16_bf16(kf3, qf3, s0, 0, 0, 0);
        __builtin_amdgcn_s_setprio(0);

        // ---- mask (diag tile only) + p = 2^s + denom, in-register ----
        float p0[16];
        const bool diag = (t == j);
        #pragma unroll
        for (int r = 0; r < 16; ++r) {
            const int cr = (r & 3) + 8 * (r >> 2) + 4 * hi;   // k row (local)
            float a = s0[r];
            if (diag && (cr > l31)) a = -1e30f;               // k_loc > q_loc
            p0[r] = __builtin_amdgcn_exp2f(a);
        }
        l_lane += SUM16(p0);

        // ---- P -> PV A-frags: cvt_pk pairs + permlane32_swap (R8-verified) ----
        unsigned int w00, w01, w02, w03, w10, w11, w12, w13;
        {
            unsigned int c0 = pkbf(p0[0], p0[1]), c1 = pkbf(p0[2], p0[3]);
            unsigned int d0 = pkbf(p0[4], p0[5]), d1 = pkbf(p0[6], p0[7]);
            asm volatile("v_permlane32_swap_b32 %0, %1" : "+v"(c0), "+v"(d0));
            asm volatile("v_permlane32_swap_b32 %0, %1" : "+v"(c1), "+v"(d1));
            w00 = c0; w01 = c1; w02 = d0; w03 = d1;
        }
        {
            unsigned int c0 = pkbf(p0[8], p0[9]),   c1 = pkbf(p0[10], p0[11]);
            unsigned int d0 = pkbf(p0[12], p0[13]), d1 = pkbf(p0[14], p0[15]);
            asm volatile("v_permlane32_swap_b32 %0, %1" : "+v"(c0), "+v"(d0));
            asm volatile("v_permlane32_swap_b32 %0, %1" : "+v"(c1), "+v"(d1));
            w10 = c0; w11 = c1; w12 = d0; w13 = d1;
        }
        uintx4 f0; f0[0] = w00; f0[1] = w01; f0[2] = w02; f0[3] = w03;
        uintx4 f1; f1[0] = w10; f1[1] = w11; f1[2] = w12; f1[3] = w13;
        const bf16x8 pa0 = __builtin_bit_cast(bf16x8, f0);   // k 0..15
        const bf16x8 pa1 = __builtin_bit_cast(bf16x8, f1);   // k 16..31

        // ---- V frags + O += P V ----
        bf16x8 vf00, vf01, vf10, vf11;
        #pragma unroll
        for (int jj = 0; jj < 8; ++jj) {
            vf00[jj] = (bf16_t)va[jj];     vf01[jj] = (bf16_t)va[8 + jj];
            vf10[jj] = (bf16_t)vb[jj];     vf11[jj] = (bf16_t)vb[8 + jj];
        }
        __builtin_amdgcn_s_setprio(1);
        oacc0 = __builtin_amdgcn_mfma_f32_32x32x16_bf16(pa0, vf00, oacc0, 0, 0, 0);
        oacc0 = __builtin_amdgcn_mfma_f32_32x32x16_bf16(pa1, vf01, oacc0, 0, 0, 0);
        oacc1 = __builtin_amdgcn_mfma_f32_32x32x16_bf16(pa0, vf10, oacc1, 0, 0, 0);
        oacc1 = __builtin_amdgcn_mfma_f32_32x32x16_bf16(pa1, vf11, oacc1, 0, 0, 0);
        __builtin_amdgcn_s_setprio(0);
    }

    // ---- split-K combine (ONE barrier pair per task), divide, store ----
    const float lden = l_lane + __shfl_xor(l_lane, 32);   // q=l31 denom, this parity

    if (grp == 1) {
        #pragma unroll
        for (int r = 0; r < 16; ++r) {
            const int cr = (r & 3) + 8 * (r >> 2) + 4 * hi;   // q row (local)
            sm.Op[cr][l31]      = oacc0[r];
            sm.Op[cr][32 + l31] = oacc1[r];
        }
        if (hi == 0) sm.den[l31] = lden;
    }
    __syncthreads();
    if (grp == 0) {
        #pragma unroll
        for (int r = 0; r < 16; ++r) {
            const int cr = (r & 3) + 8 * (r >> 2) + 4 * hi;
            const float dA = __shfl(lden, cr);      // own parity, q=cr
            const float dB = sm.den[cr];            // other parity
            const float inv = 1.f / (dA + dB);
            const long orow = qb + (long)cr * Dq;
            O[orow + l31]      = (oacc0[r] + sm.Op[cr][l31]) * inv;
            O[orow + 32 + l31] = (oacc1[r] + sm.Op[cr][32 + l31]) * inv;
        }
    }
}

extern "C" void kernel_launch(void* const* d_in, const int* in_sizes, int n_in,
                              void* d_out, int out_size, void* d_ws, size_t ws_size,
                              hipStream_t stream)
{
    const float* q = (const float*)d_in[0];
    const float* k = (const float*)d_in[1];
    const float* v = (const float*)d_in[2];
    float* out = (float*)d_out;
    // d_in[3] (mask) is the static causal mask; handled analytically in-kernel.
    flash_attn_kernel<<<dim3(2048, 1, 1), dim3(128, 1, 1), 0, stream>>>(q, k, v, out);
}